// Round 1
// baseline (684.881 us; speedup 1.0000x reference)
//
#include <hip/hip_runtime.h>

// ---------------------------------------------------------------------------
// Segment-mean over contiguous segments.
//   in[0]: node_feats  (N_TOTAL=524288, D=256) float32
//   in[1]: n_nodes     (B=4096) int32, sums to N_TOTAL
//   out  : graph_feats (B, D) float32
// Segments are contiguous row ranges -> exclusive-scan n_nodes, then one
// wave per graph does a dense float4 column-parallel reduction.
// ---------------------------------------------------------------------------

#define B_GRAPHS 4096
#define DIM 256
#define SCAN_THREADS 256
#define PER_THREAD (B_GRAPHS / SCAN_THREADS)  // 16

// Kernel 1: exclusive prefix sum of n_nodes into offsets (d_ws).
__global__ __launch_bounds__(SCAN_THREADS) void scan_offsets(
    const int* __restrict__ n_nodes, int* __restrict__ offsets) {
  __shared__ int tsum[SCAN_THREADS];
  const int t = threadIdx.x;

  int vals[PER_THREAD];
  int s = 0;
#pragma unroll
  for (int i = 0; i < PER_THREAD; ++i) {
    vals[i] = n_nodes[t * PER_THREAD + i];
    s += vals[i];
  }
  tsum[t] = s;
  __syncthreads();

  // Hillis-Steele inclusive scan over thread totals (8 steps for 256).
#pragma unroll
  for (int d = 1; d < SCAN_THREADS; d <<= 1) {
    int add = (t >= d) ? tsum[t - d] : 0;
    __syncthreads();
    tsum[t] += add;
    __syncthreads();
  }

  int excl = (t == 0) ? 0 : tsum[t - 1];
#pragma unroll
  for (int i = 0; i < PER_THREAD; ++i) {
    offsets[t * PER_THREAD + i] = excl;
    excl += vals[i];
  }
}

// Kernel 2: one 64-lane wave per graph; lane i accumulates float4 of
// columns [4i, 4i+4) over the graph's contiguous row range.
__global__ __launch_bounds__(256) void seg_mean(
    const float* __restrict__ feats, const int* __restrict__ n_nodes,
    const int* __restrict__ offsets, float* __restrict__ out) {
  const int tid = threadIdx.x;
  const int lane = tid & 63;
  const int g = blockIdx.x * 4 + (tid >> 6);  // 4 waves -> 4 graphs per block

  const int start = offsets[g];
  const int n = n_nodes[g];

  // Row-major float4 view: row r begins at float4 index r*64.
  const float4* __restrict__ src =
      reinterpret_cast<const float4*>(feats) + (size_t)start * 64 + lane;

  float4 a0 = make_float4(0.f, 0.f, 0.f, 0.f);
  float4 a1 = a0, a2 = a0, a3 = a0;

  int r = 0;
  for (; r + 4 <= n; r += 4) {
    float4 v0 = src[(size_t)(r + 0) * 64];
    float4 v1 = src[(size_t)(r + 1) * 64];
    float4 v2 = src[(size_t)(r + 2) * 64];
    float4 v3 = src[(size_t)(r + 3) * 64];
    a0.x += v0.x; a0.y += v0.y; a0.z += v0.z; a0.w += v0.w;
    a1.x += v1.x; a1.y += v1.y; a1.z += v1.z; a1.w += v1.w;
    a2.x += v2.x; a2.y += v2.y; a2.z += v2.z; a2.w += v2.w;
    a3.x += v3.x; a3.y += v3.y; a3.z += v3.z; a3.w += v3.w;
  }
  for (; r < n; ++r) {
    float4 v = src[(size_t)r * 64];
    a0.x += v.x; a0.y += v.y; a0.z += v.z; a0.w += v.w;
  }

  float4 acc;
  acc.x = (a0.x + a1.x) + (a2.x + a3.x);
  acc.y = (a0.y + a1.y) + (a2.y + a3.y);
  acc.z = (a0.z + a1.z) + (a2.z + a3.z);
  acc.w = (a0.w + a1.w) + (a2.w + a3.w);

  const float inv = 1.0f / (float)n;
  acc.x *= inv; acc.y *= inv; acc.z *= inv; acc.w *= inv;

  reinterpret_cast<float4*>(out)[(size_t)g * 64 + lane] = acc;
}

extern "C" void kernel_launch(void* const* d_in, const int* in_sizes, int n_in,
                              void* d_out, int out_size, void* d_ws, size_t ws_size,
                              hipStream_t stream) {
  const float* node_feats = (const float*)d_in[0];
  const int* n_nodes = (const int*)d_in[1];
  float* out = (float*)d_out;
  int* offsets = (int*)d_ws;  // B_GRAPHS ints = 16 KB

  scan_offsets<<<1, SCAN_THREADS, 0, stream>>>(n_nodes, offsets);
  seg_mean<<<B_GRAPHS / 4, 256, 0, stream>>>(node_feats, n_nodes, offsets, out);
}

// Round 2
// 682.549 us; speedup vs baseline: 1.0034x; 1.0034x over previous
//
#include <hip/hip_runtime.h>

// ---------------------------------------------------------------------------
// Segment-mean over contiguous segments (single fused kernel).
//   in[0]: node_feats  (N_TOTAL=524288, D=256) float32
//   in[1]: n_nodes     (B=4096) int32, sums to N_TOTAL
//   out  : graph_feats (B, D) float32
//
// Segments are contiguous row ranges. Each block handles 4 graphs (1 wave
// per graph). The block computes its base offset = sum(n_nodes[0..g0)) with
// a strided read + LDS tree reduce (16 KB working set, L2-resident across
// all blocks), then each wave streams its graph's rows: lane i owns columns
// [4i,4i+4) as a float4 accumulator, 8 rows in flight for latency hiding.
// ---------------------------------------------------------------------------

#define BLOCK 256
#define GPB 4  // graphs per block (= waves per block)

typedef float f4 __attribute__((ext_vector_type(4)));

__global__ __launch_bounds__(BLOCK) void seg_mean_fused(
    const float* __restrict__ feats,
    const int* __restrict__ n_nodes,
    float* __restrict__ out) {
  __shared__ int red[BLOCK];
  __shared__ int offs[GPB];

  const int t = threadIdx.x;
  const int g0 = blockIdx.x * GPB;

  // ---- base = sum(n_nodes[0..g0)), coalesced strided read + tree reduce ----
  int s = 0;
  for (int i = t; i < g0; i += BLOCK) s += n_nodes[i];
  red[t] = s;
  __syncthreads();
#pragma unroll
  for (int d = BLOCK / 2; d > 0; d >>= 1) {
    if (t < d) red[t] += red[t + d];
    __syncthreads();
  }
  if (t == 0) {
    int o = red[0];
#pragma unroll
    for (int j = 0; j < GPB; ++j) {
      offs[j] = o;
      o += n_nodes[g0 + j];
    }
  }
  __syncthreads();

  // ---- one wave per graph: dense column-parallel reduction ----
  const int wave = t >> 6;
  const int lane = t & 63;
  const int g = g0 + wave;
  const int n = n_nodes[g];
  const int start = offs[wave];

  // Row-major f4 view: row r of this graph begins at f4 index (start+r)*64.
  const f4* __restrict__ src =
      reinterpret_cast<const f4*>(feats) + (size_t)start * 64 + lane;

  f4 acc[8];
#pragma unroll
  for (int i = 0; i < 8; ++i) acc[i] = (f4)0.0f;

  int r = 0;
  for (; r + 8 <= n; r += 8) {
#pragma unroll
    for (int i = 0; i < 8; ++i) {
      acc[i] += src[(size_t)(r + i) * 64];  // 64 lanes x 16 B = one 1 KiB row
    }
  }
  for (; r < n; ++r) acc[0] += src[(size_t)r * 64];

  f4 total = ((acc[0] + acc[1]) + (acc[2] + acc[3])) +
             ((acc[4] + acc[5]) + (acc[6] + acc[7]));
  total *= (1.0f / (float)n);

  reinterpret_cast<f4*>(out)[(size_t)g * 64 + lane] = total;
}

extern "C" void kernel_launch(void* const* d_in, const int* in_sizes, int n_in,
                              void* d_out, int out_size, void* d_ws, size_t ws_size,
                              hipStream_t stream) {
  const float* node_feats = (const float*)d_in[0];
  const int* n_nodes = (const int*)d_in[1];
  float* out = (float*)d_out;

  const int b = in_sizes[1];  // 4096 graphs
  seg_mean_fused<<<b / GPB, BLOCK, 0, stream>>>(node_feats, n_nodes, out);
}

// Round 3
// 643.789 us; speedup vs baseline: 1.0638x; 1.0602x over previous
//
#include <hip/hip_runtime.h>

// ---------------------------------------------------------------------------
// Segment-mean over contiguous segments (single fused kernel).
//   in[0]: node_feats  (N_TOTAL=524288, D=256) float32   -- 512 MB, read once
//   in[1]: n_nodes     (B=4096) int32, sums to N_TOTAL
//   out  : graph_feats (B, D) float32                    -- 4 MB
//
// One wave per graph; lane i owns columns [4i,4i+4) as a float4 accumulator.
// Each block of 4 waves computes its base offset by summing the n_nodes
// prefix (16 KB, L2-resident). Feature stream uses nontemporal loads
// (read-once, no reuse -> don't pollute L2/L3).
// ---------------------------------------------------------------------------

#define BLOCK 256
#define GPB 4  // graphs per block (= waves per block)

typedef float f4 __attribute__((ext_vector_type(4)));

__global__ __launch_bounds__(BLOCK) void seg_mean_fused(
    const float* __restrict__ feats,
    const int* __restrict__ n_nodes,
    float* __restrict__ out) {
  __shared__ int red[BLOCK];
  __shared__ int offs[GPB];

  const int t = threadIdx.x;
  const int g0 = blockIdx.x * GPB;

  // ---- base = sum(n_nodes[0..g0)), coalesced strided read + tree reduce ----
  int s = 0;
  for (int i = t; i < g0; i += BLOCK) s += n_nodes[i];
  red[t] = s;
  __syncthreads();
#pragma unroll
  for (int d = BLOCK / 2; d > 0; d >>= 1) {
    if (t < d) red[t] += red[t + d];
    __syncthreads();
  }
  if (t == 0) {
    int o = red[0];
#pragma unroll
    for (int j = 0; j < GPB; ++j) {
      offs[j] = o;
      o += n_nodes[g0 + j];
    }
  }
  __syncthreads();

  // ---- one wave per graph: dense column-parallel reduction ----
  const int wave = t >> 6;
  const int lane = t & 63;
  const int g = g0 + wave;
  const int n = n_nodes[g];
  const int start = offs[wave];

  // Row-major f4 view: row r of this graph begins at f4 index (start+r)*64.
  const f4* __restrict__ src =
      reinterpret_cast<const f4*>(feats) + (size_t)start * 64 + lane;

  f4 acc[8];
#pragma unroll
  for (int i = 0; i < 8; ++i) acc[i] = (f4)0.0f;

  int r = 0;
  for (; r + 8 <= n; r += 8) {
#pragma unroll
    for (int i = 0; i < 8; ++i) {
      // read-once stream: nontemporal load (1 KiB per wave per instr)
      acc[i] += __builtin_nontemporal_load(&src[(size_t)(r + i) * 64]);
    }
  }
  for (; r < n; ++r) acc[0] += __builtin_nontemporal_load(&src[(size_t)r * 64]);

  f4 total = ((acc[0] + acc[1]) + (acc[2] + acc[3])) +
             ((acc[4] + acc[5]) + (acc[6] + acc[7]));
  total *= (1.0f / (float)n);

  __builtin_nontemporal_store(
      total, &reinterpret_cast<f4*>(out)[(size_t)g * 64 + lane]);
}

extern "C" void kernel_launch(void* const* d_in, const int* in_sizes, int n_in,
                              void* d_out, int out_size, void* d_ws, size_t ws_size,
                              hipStream_t stream) {
  const float* node_feats = (const float*)d_in[0];
  const int* n_nodes = (const int*)d_in[1];
  float* out = (float*)d_out;

  const int b = in_sizes[1];  // 4096 graphs
  seg_mean_fused<<<b / GPB, BLOCK, 0, stream>>>(node_feats, n_nodes, out);
}